// Round 5
// baseline (436.138 us; speedup 1.0000x reference)
//
#include <hip/hip_runtime.h>
#include <hip/hip_bf16.h>

// Spatial RNN, 4 directions, R=8, C=64.
// One block per (direction, line). Reversed directions via negative strides so
// the recurrence is always t[p] = relu(t[p-1] @ W), t[-1] = 0.
//
// v6 = v3 structure at the proven no-spill launch bound:
//  - __launch_bounds__(256,4): VGPR cap 128. (256,5)/(256,6) capped the
//    unified file at ~102/~85 -> acc/Af spilled to scratch (hbm 3.2-4.2GB).
//    At ~88-102 VGPRs the HW can still co-schedule 5 blocks/CU (LDS 128KB,
//    waves/SIMD floor(512/VGPR)=5): the bound is an allocator floor, not a
//    residency ceiling.
//  - Read ALL 6 B fragments up front each step (3 independent chains), THEN
//    compute + in-place write. Per-wave LDS program order guarantees the
//    reads precede the overwrites; v5's per-tile read->MFMA->write order
//    serialized the LDS pipe behind the MFMA/VALU chain (174us vs v2 160us).
//  - Contiguous wave ownership (wave wv owns pixels [48wv,48wv+48)) with the
//    single cross-wave boundary pixel routed through parity-double-buffered
//    bnd rows -> ONE __syncthreads per step.
//  - 128B rows, 16B-granule XOR swizzle (g' = g ^ (slot&7)): reads and writes
//    both at 2 lanes/bank (free per m136). LDS = 25,600B.
//  - 1-D grid, batch = bid&7: one batch per XCD (L2 locality); L/R (and U/D)
//    of the same line are dispatch-adjacent on the same XCD.

#define HD 192
#define CH 64
#define RSTEPS 8
#define TS 64               // shorts per row = 128B, XOR-swizzled
#define SLOTS 192           // slot p+1 holds t[p]; slot 0 = t[-1] = 0
#define BND (SLOTS * TS)    // 8 boundary rows: row = parity*4 + wave

typedef __attribute__((ext_vector_type(8))) short short8v;
typedef __attribute__((ext_vector_type(4))) float float4v;

static __device__ __forceinline__ short f2bf_rne(float f) {
    unsigned u = __float_as_uint(f);
    u += 0x7FFFu + ((u >> 16) & 1u);
    return (short)(u >> 16);
}

__global__ __launch_bounds__(256, 4) void spatial_rnn_kernel(
    const float* __restrict__ x,
    const float* __restrict__ Wl,
    const float* __restrict__ Wr,
    const float* __restrict__ Wu,
    const float* __restrict__ Wd,
    float* __restrict__ out)
{
    __shared__ __align__(16) short tb[SLOTS * TS + 8 * TS];   // 25,600 B

    const int tid = threadIdx.x;
    const int bid = blockIdx.x;
    const int b   = bid & 7;
    const int idx = bid >> 3;
    const int dir = idx & 3;
    const int rc  = idx >> 2;          // row (L/R) or column (U/D), [0,192)

    const float* Wp = (dir == 0) ? Wl : (dir == 1) ? Wr : (dir == 2) ? Wu : Wd;

    int xbase, xstride, obase, ostride;
    if (dir == 0) {        // left: out[w] uses in[w-1]; forward along w
        xbase   = (b * HD + rc) * HD * CH;
        xstride = CH;
        obase   = (b * HD + rc) * HD * 256;
        ostride = 256;
    } else if (dir == 1) { // right: out[w] uses in[w+1]; reversed along w
        xbase   = ((b * HD + rc) * HD + (HD - 1)) * CH;
        xstride = -CH;
        obase   = ((b * HD + rc) * HD + (HD - 1)) * 256 + 64;
        ostride = -256;
    } else if (dir == 2) { // up: out[h] uses in[h-1]; forward along h
        xbase   = b * HD * HD * CH + rc * CH;
        xstride = HD * CH;
        obase   = b * HD * HD * 256 + rc * 256 + 128;
        ostride = HD * 256;
    } else {               // down: out[h] uses in[h+1]; reversed along h
        xbase   = ((b * HD + (HD - 1)) * HD + rc) * CH;
        xstride = -HD * CH;
        obase   = ((b * HD + (HD - 1)) * HD + rc) * 256 + 192;
        ostride = -HD * 256;
    }

    const int lane = tid & 63;
    const int wv   = tid >> 6;
    const int q4   = lane >> 4;
    const int l16  = lane & 15;

    // zero slot-0 row (t[-1]); swizzled zeros are still zeros
    if (tid < 32) ((int*)tb)[tid] = 0;

    // ---- x fragment loads: acc init (folds final "+x") + t0 -> LDS ----
    float4v acc[3][4];
    #pragma unroll
    for (int i = 0; i < 3; ++i) {
        const int p   = (3 * wv + i) * 16 + l16;     // contiguous ownership
        const int wsz = (l16 + 1) & 7;               // == (slot&7); 0 at boundary
        int wbase = (p + 1) * TS;
        if (i == 2 && l16 == 15) wbase = BND + (4 + wv) * TS;  // parity-1 bnd
        #pragma unroll
        for (int dt = 0; dt < 4; ++dt) {
            const float4 v = *(const float4*)(x + xbase + p * xstride + dt * 16 + q4 * 4);
            acc[i][dt] = (float4v){v.x, v.y, v.z, v.w};
            __hip_bfloat162 h01 = __float22bfloat162_rn(make_float2(v.x, v.y));
            __hip_bfloat162 h23 = __float22bfloat162_rn(make_float2(v.z, v.w));
            uint2 wpk;
            __builtin_memcpy(&wpk.x, &h01, 4);
            __builtin_memcpy(&wpk.y, &h23, 4);
            *(uint2*)(tb + wbase + (((2 * dt + (q4 >> 1)) ^ wsz) << 3) + ((q4 & 1) << 2)) = wpk;
        }
    }

    // ---- W fragments (A operand): A[d][c] = W[c][d] ----
    short8v Af[2][4];
    #pragma unroll
    for (int kc = 0; kc < 2; ++kc)
        #pragma unroll
        for (int dt = 0; dt < 4; ++dt)
            #pragma unroll
            for (int j = 0; j < 8; ++j)
                Af[kc][dt][j] = f2bf_rne(Wp[(kc * 32 + q4 * 8 + j) * CH + dt * 16 + l16]);

    __syncthreads();

    // ---- 8 recurrent steps, in place, ONE barrier per step ----
    for (int k = 0; k < RSTEPS; ++k) {
        short8v B0[3], B1[3];
        const int prb = ((k & 1) ^ 1) << 2;          // read-parity bnd offset
        #pragma unroll
        for (int i = 0; i < 3; ++i) {
            const int slot = (3 * wv + i) * 16 + l16;   // holds t_prev[slot-1]
            const int sz   = l16 & 7;                    // == slot&7; 0 at boundary
            int base = slot * TS;
            if (i == 0 && l16 == 0 && wv > 0) base = BND + (prb + wv - 1) * TS;
            B0[i] = *(const short8v*)(tb + base + ((q4 ^ sz) << 3));
            B1[i] = *(const short8v*)(tb + base + (((q4 + 4) ^ sz) << 3));
        }
        // wave-private in-place writes (LDS pipe is in-order per wave)
        #pragma unroll
        for (int i = 0; i < 3; ++i) {
            const int wsz = (l16 + 1) & 7;
            int wbase = ((3 * wv + i) * 16 + l16 + 1) * TS;
            if (i == 2 && l16 == 15) wbase = BND + (((k & 1) << 2) + wv) * TS;
            #pragma unroll
            for (int dt = 0; dt < 4; ++dt) {
                float4v d = {0.f, 0.f, 0.f, 0.f};
                d = __builtin_amdgcn_mfma_f32_16x16x32_bf16(Af[0][dt], B0[i], d, 0, 0, 0);
                d = __builtin_amdgcn_mfma_f32_16x16x32_bf16(Af[1][dt], B1[i], d, 0, 0, 0);
                float v0 = fmaxf(d[0], 0.f);
                float v1 = fmaxf(d[1], 0.f);
                float v2 = fmaxf(d[2], 0.f);
                float v3 = fmaxf(d[3], 0.f);
                acc[i][dt][0] += v0; acc[i][dt][1] += v1;
                acc[i][dt][2] += v2; acc[i][dt][3] += v3;
                if (k < RSTEPS - 1) {
                    __hip_bfloat162 h01 = __float22bfloat162_rn(make_float2(v0, v1));
                    __hip_bfloat162 h23 = __float22bfloat162_rn(make_float2(v2, v3));
                    uint2 wpk;
                    __builtin_memcpy(&wpk.x, &h01, 4);
                    __builtin_memcpy(&wpk.y, &h23, 4);
                    *(uint2*)(tb + wbase + (((2 * dt + (q4 >> 1)) ^ wsz) << 3) + ((q4 & 1) << 2)) = wpk;
                }
            }
        }
        if (k < RSTEPS - 1) __syncthreads();
    }

    // ---- store: out = acc (x folded in at init) ----
    // lanes q4=0..3 of one pixel cover 64B contiguous -> full write sectors
    #pragma unroll
    for (int i = 0; i < 3; ++i) {
        const int p = (3 * wv + i) * 16 + l16;
        #pragma unroll
        for (int dt = 0; dt < 4; ++dt) {
            float4 o;
            o.x = acc[i][dt][0]; o.y = acc[i][dt][1];
            o.z = acc[i][dt][2]; o.w = acc[i][dt][3];
            *(float4*)(out + obase + p * ostride + dt * 16 + q4 * 4) = o;
        }
    }
}

extern "C" void kernel_launch(void* const* d_in, const int* in_sizes, int n_in,
                              void* d_out, int out_size, void* d_ws, size_t ws_size,
                              hipStream_t stream) {
    const float* x  = (const float*)d_in[0];
    const float* Wl = (const float*)d_in[1];
    const float* Wr = (const float*)d_in[2];
    const float* Wu = (const float*)d_in[3];
    const float* Wd = (const float*)d_in[4];
    float* outp = (float*)d_out;
    dim3 grid(8 * HD * 4);
    spatial_rnn_kernel<<<grid, 256, 0, stream>>>(x, Wl, Wr, Wu, Wd, outp);
}